// Round 1
// baseline (1697.312 us; speedup 1.0000x reference)
//
#include <hip/hip_runtime.h>
#include <math.h>

#define NN 50000
#define DD 128
#define EE 800000

static constexpr float BN_EPS = 1e-3f;

__device__ __forceinline__ float gelu_f(float x) {
    // exact GELU: 0.5*x*(1+erf(x/sqrt(2)))
    return 0.5f * x * (1.0f + erff(x * 0.7071067811865475f));
}

// ---------------- BN-fold kernels ----------------
// W' [K][128] = s[k]*W[k][j],  s = g*rsqrt(v+eps)
__global__ void fold_w(const float* __restrict__ W, const float* __restrict__ g,
                       const float* __restrict__ v, float* __restrict__ Wf, int total) {
    int idx = blockIdx.x * blockDim.x + threadIdx.x;
    if (idx >= total) return;
    int k = idx >> 7;  // 128 cols
    float s = g[k] * rsqrtf(v[k] + BN_EPS);
    Wf[idx] = s * W[idx];
}

// b'[j] = bias[j] + sum_k (b[k]-m[k]*s[k]) * W[k][j]
__global__ void fold_b(const float* __restrict__ W, const float* __restrict__ g,
                       const float* __restrict__ bb, const float* __restrict__ m,
                       const float* __restrict__ v, const float* __restrict__ bias,
                       float* __restrict__ bf, int K) {
    int j = threadIdx.x;  // 128 threads
    float acc = 0.f;
    for (int k = 0; k < K; ++k) {
        float s = g[k] * rsqrtf(v[k] + BN_EPS);
        float t = bb[k] - m[k] * s;
        acc = fmaf(t, W[k * DD + j], acc);
    }
    bf[j] = bias[j] + acc;
}

// ---------------- shared GEMM chunk: C[64or128 rows][128] += X[rows][32] @ W[32][128] ----
// NT = threads/block, XLD = LDS row stride of X. Each thread owns 8 rows x 4 cols.
// Wc is a [32][128] LDS buffer; Wrow0 points at the folded weight chunk (row kc*32).
template<int NT, int XLD>
__device__ __forceinline__ void gemm_k32(const float* __restrict__ Wrow0,
                                         const float* __restrict__ A,
                                         float* __restrict__ Wc,
                                         int t, int r0, int c0, int xoff,
                                         float acc[8][4])
{
    __syncthreads();  // previous users of Wc (and pending LDS writes) done
    #pragma unroll
    for (int i = 0; i < 1024 / NT; ++i) {   // 32*128 floats = 1024 float4
        int q = i * NT + t;
        int kk = q >> 5, c4 = q & 31;
        *reinterpret_cast<float4*>(Wc + kk * DD + (c4 << 2)) =
            *reinterpret_cast<const float4*>(Wrow0 + (size_t)kk * DD + (c4 << 2));
    }
    __syncthreads();
    #pragma unroll
    for (int kk = 0; kk < 32; kk += 4) {
        float4 w0 = *reinterpret_cast<const float4*>(Wc + (kk + 0) * DD + c0);
        float4 w1 = *reinterpret_cast<const float4*>(Wc + (kk + 1) * DD + c0);
        float4 w2 = *reinterpret_cast<const float4*>(Wc + (kk + 2) * DD + c0);
        float4 w3 = *reinterpret_cast<const float4*>(Wc + (kk + 3) * DD + c0);
        #pragma unroll
        for (int i = 0; i < 8; ++i) {
            float4 x = *reinterpret_cast<const float4*>(A + (r0 + i) * XLD + xoff + kk);
            acc[i][0] = fmaf(x.x, w0.x, fmaf(x.y, w1.x, fmaf(x.z, w2.x, fmaf(x.w, w3.x, acc[i][0]))));
            acc[i][1] = fmaf(x.x, w0.y, fmaf(x.y, w1.y, fmaf(x.z, w2.y, fmaf(x.w, w3.y, acc[i][1]))));
            acc[i][2] = fmaf(x.x, w0.z, fmaf(x.y, w1.z, fmaf(x.z, w2.z, fmaf(x.w, w3.z, acc[i][2]))));
            acc[i][3] = fmaf(x.x, w0.w, fmaf(x.y, w1.w, fmaf(x.z, w2.w, fmaf(x.w, w3.w, acc[i][3]))));
        }
    }
}

// ---------------- edge kernel: gather -> FFN(2 layers) -> *ew -> atomic scatter ----
// 128 edges/block, 512 threads. LDS: A[128][128] (X aliased with Y) + Wc[32][128] = 80 KB
// -> 2 blocks/CU, 16 waves/CU.
__global__ __launch_bounds__(512, 4) void edge_kernel(
    const float* __restrict__ reps, const int* __restrict__ edges,
    const float* __restrict__ ew,
    const float* __restrict__ W1, const float* __restrict__ B1,
    const float* __restrict__ W2, const float* __restrict__ B2,
    float* __restrict__ agg)
{
    extern __shared__ float lds[];
    float* A  = lds;              // 128*128
    float* Wc = lds + 128 * 128;  // 32*128
    const int t  = threadIdx.x;
    const int e0 = blockIdx.x * 128;
    const int* nbr = edges + EE;  // edges row 1

    // gather 128 neighbour rows into A (coalesced float4 within each 512B row)
    #pragma unroll
    for (int i = 0; i < 8; ++i) {
        int q = i * 512 + t;          // 0..4095 float4 slots
        int r = q >> 5, c4 = q & 31;
        int nb = nbr[e0 + r];
        *reinterpret_cast<float4*>(A + r * DD + (c4 << 2)) =
            *reinterpret_cast<const float4*>(reps + (size_t)nb * DD + (c4 << 2));
    }

    const int rg = t >> 5, cg = t & 31;
    const int r0 = rg << 3, c0 = cg << 2;
    float acc[8][4];

    // ---- layer 1 ----
    #pragma unroll
    for (int i = 0; i < 8; ++i) { acc[i][0] = acc[i][1] = acc[i][2] = acc[i][3] = 0.f; }
    for (int kc = 0; kc < 4; ++kc)
        gemm_k32<512, DD>(W1 + (size_t)kc * 32 * DD, A, Wc, t, r0, c0, kc * 32, acc);
    __syncthreads();  // all reads of A done -> safe to overwrite with Y
    {
        float4 b = *reinterpret_cast<const float4*>(B1 + c0);
        #pragma unroll
        for (int i = 0; i < 8; ++i) {
            float4 o;
            o.x = gelu_f(acc[i][0] + b.x);
            o.y = gelu_f(acc[i][1] + b.y);
            o.z = gelu_f(acc[i][2] + b.z);
            o.w = gelu_f(acc[i][3] + b.w);
            *reinterpret_cast<float4*>(A + (r0 + i) * DD + c0) = o;
        }
    }

    // ---- layer 2 ---- (gemm_k32's leading sync makes Y visible)
    #pragma unroll
    for (int i = 0; i < 8; ++i) { acc[i][0] = acc[i][1] = acc[i][2] = acc[i][3] = 0.f; }
    for (int kc = 0; kc < 4; ++kc)
        gemm_k32<512, DD>(W2 + (size_t)kc * 32 * DD, A, Wc, t, r0, c0, kc * 32, acc);

    // ---- scale by edge weight, scatter-add ----
    {
        float4 b = *reinterpret_cast<const float4*>(B2 + c0);
        #pragma unroll
        for (int i = 0; i < 8; ++i) {
            int e = e0 + r0 + i;
            float w = ew[e];
            int node = edges[e];  // edges row 0
            float* dst = agg + (size_t)node * DD + c0;
            atomicAdd(dst + 0, gelu_f(acc[i][0] + b.x) * w);
            atomicAdd(dst + 1, gelu_f(acc[i][1] + b.y) * w);
            atomicAdd(dst + 2, gelu_f(acc[i][2] + b.z) * w);
            atomicAdd(dst + 3, gelu_f(acc[i][3] + b.w) * w);
        }
    }
}

// ---------------- node kernel: concat -> FFN(2 layers) -> L2 normalize ----
// 64 nodes/block, 256 threads. LDS: A[64][256] + Wc[32][128] = 80 KB -> 2 blocks/CU.
__global__ __launch_bounds__(256, 2) void node_kernel(
    const float* __restrict__ reps, const float* __restrict__ agg,
    const float* __restrict__ U1, const float* __restrict__ C1,
    const float* __restrict__ U2, const float* __restrict__ C2,
    float* __restrict__ out)
{
    extern __shared__ float lds[];
    float* A  = lds;              // 64*256 (concat; Y reuses cols 0..127)
    float* Wc = lds + 64 * 256;   // 32*128
    const int t  = threadIdx.x;
    const int n0 = blockIdx.x * 64;

    // stage concat [reps | agg]
    #pragma unroll
    for (int i = 0; i < 16; ++i) {
        int q = i * 256 + t;          // float4 index 0..4095
        int r = q >> 6, c4 = q & 63;
        int n = n0 + r; if (n >= NN) n = NN - 1;  // clamp tail (stores skipped)
        const float* src = (c4 < 32) ? (reps + (size_t)n * DD + (c4 << 2))
                                     : (agg  + (size_t)n * DD + ((c4 - 32) << 2));
        *reinterpret_cast<float4*>(A + r * 256 + (c4 << 2)) =
            *reinterpret_cast<const float4*>(src);
    }

    const int rg = t >> 5, cg = t & 31;
    const int r0 = rg << 3, c0 = cg << 2;
    float acc[8][4];

    // ---- update layer 1: K=256 ----
    #pragma unroll
    for (int i = 0; i < 8; ++i) { acc[i][0] = acc[i][1] = acc[i][2] = acc[i][3] = 0.f; }
    for (int kc = 0; kc < 8; ++kc)
        gemm_k32<256, 256>(U1 + (size_t)kc * 32 * DD, A, Wc, t, r0, c0, kc * 32, acc);
    __syncthreads();
    {
        float4 b = *reinterpret_cast<const float4*>(C1 + c0);
        #pragma unroll
        for (int i = 0; i < 8; ++i) {
            float4 o;
            o.x = gelu_f(acc[i][0] + b.x);
            o.y = gelu_f(acc[i][1] + b.y);
            o.z = gelu_f(acc[i][2] + b.z);
            o.w = gelu_f(acc[i][3] + b.w);
            *reinterpret_cast<float4*>(A + (r0 + i) * 256 + c0) = o;
        }
    }

    // ---- update layer 2: K=128 (Y lives in cols 0..127 of A, stride 256) ----
    #pragma unroll
    for (int i = 0; i < 8; ++i) { acc[i][0] = acc[i][1] = acc[i][2] = acc[i][3] = 0.f; }
    for (int kc = 0; kc < 4; ++kc)
        gemm_k32<256, 256>(U2 + (size_t)kc * 32 * DD, A, Wc, t, r0, c0, kc * 32, acc);

    // ---- bias + GELU + L2 normalize + store ----
    {
        float4 b = *reinterpret_cast<const float4*>(C2 + c0);
        #pragma unroll
        for (int i = 0; i < 8; ++i) {
            float v0 = gelu_f(acc[i][0] + b.x);
            float v1 = gelu_f(acc[i][1] + b.y);
            float v2 = gelu_f(acc[i][2] + b.z);
            float v3 = gelu_f(acc[i][3] + b.w);
            float ss = v0 * v0 + v1 * v1 + v2 * v2 + v3 * v3;
            // row spans the 32-lane group this thread sits in (lanes 0..31 or 32..63)
            #pragma unroll
            for (int msk = 1; msk < 32; msk <<= 1) ss += __shfl_xor(ss, msk);
            float sc = rsqrtf(fmaxf(ss, 1e-12f));
            int n = n0 + r0 + i;
            if (n < NN) {
                float4 o = { v0 * sc, v1 * sc, v2 * sc, v3 * sc };
                *reinterpret_cast<float4*>(out + (size_t)n * DD + c0) = o;
            }
        }
    }
}

// ---------------- launch ----------------
extern "C" void kernel_launch(void* const* d_in, const int* in_sizes, int n_in,
                              void* d_out, int out_size, void* d_ws, size_t ws_size,
                              hipStream_t stream)
{
    const float* reps = (const float*)d_in[0];
    const int*   edges = (const int*)d_in[1];
    const float* ew   = (const float*)d_in[2];
    const float* bn1g = (const float*)d_in[3];
    const float* bn1b = (const float*)d_in[4];
    const float* bn1m = (const float*)d_in[5];
    const float* bn1v = (const float*)d_in[6];
    const float* w1   = (const float*)d_in[7];
    const float* b1   = (const float*)d_in[8];
    const float* bn2g = (const float*)d_in[9];
    const float* bn2b = (const float*)d_in[10];
    const float* bn2m = (const float*)d_in[11];
    const float* bn2v = (const float*)d_in[12];
    const float* w2   = (const float*)d_in[13];
    const float* b2   = (const float*)d_in[14];
    const float* ubn1g = (const float*)d_in[15];
    const float* ubn1b = (const float*)d_in[16];
    const float* ubn1m = (const float*)d_in[17];
    const float* ubn1v = (const float*)d_in[18];
    const float* u1    = (const float*)d_in[19];
    const float* ub1   = (const float*)d_in[20];
    const float* ubn2g = (const float*)d_in[21];
    const float* ubn2b = (const float*)d_in[22];
    const float* ubn2m = (const float*)d_in[23];
    const float* ubn2v = (const float*)d_in[24];
    const float* u2    = (const float*)d_in[25];
    const float* ub2   = (const float*)d_in[26];

    // workspace layout (floats)
    float* ws  = (float*)d_ws;
    float* W1f = ws;                 // 16384
    float* B1f = ws + 16384;         // 128
    float* W2f = ws + 16512;         // 16384
    float* B2f = ws + 32896;         // 128
    float* U1f = ws + 33024;         // 32768
    float* C1f = ws + 65792;         // 128
    float* U2f = ws + 65920;         // 16384
    float* C2f = ws + 82304;         // 128
    float* agg = ws + 82432;         // 6400000
    if (ws_size < (size_t)(82432 + NN * DD) * sizeof(float)) return;

    fold_w<<<64,  256, 0, stream>>>(w1, bn1g, bn1v, W1f, 16384);
    fold_b<<<1,   128, 0, stream>>>(w1, bn1g, bn1b, bn1m, bn1v, b1, B1f, 128);
    fold_w<<<64,  256, 0, stream>>>(w2, bn2g, bn2v, W2f, 16384);
    fold_b<<<1,   128, 0, stream>>>(w2, bn2g, bn2b, bn2m, bn2v, b2, B2f, 128);
    fold_w<<<128, 256, 0, stream>>>(u1, ubn1g, ubn1v, U1f, 32768);
    fold_b<<<1,   128, 0, stream>>>(u1, ubn1g, ubn1b, ubn1m, ubn1v, ub1, C1f, 256);
    fold_w<<<64,  256, 0, stream>>>(u2, ubn2g, ubn2v, U2f, 16384);
    fold_b<<<1,   128, 0, stream>>>(u2, ubn2g, ubn2b, ubn2m, ubn2v, ub2, C2f, 128);

    hipMemsetAsync(agg, 0, (size_t)NN * DD * sizeof(float), stream);

    const int edge_lds = (128 * 128 + 32 * 128) * sizeof(float);  // 80 KB
    edge_kernel<<<EE / 128, 512, edge_lds, stream>>>(reps, edges, ew, W1f, B1f, W2f, B2f, agg);

    const int node_lds = (64 * 256 + 32 * 128) * sizeof(float);   // 80 KB
    node_kernel<<<(NN + 63) / 64, 256, node_lds, stream>>>(reps, agg, U1f, C1f, U2f, C2f, (float*)d_out);
}

// Round 4
// 656.557 us; speedup vs baseline: 2.5852x; 2.5852x over previous
//
#include <hip/hip_runtime.h>
#include <math.h>

#define NN 50000
#define DD 128
#define EE 800000

static constexpr float BN_EPS = 1e-3f;

typedef __attribute__((ext_vector_type(8))) short bf16x8;
typedef __attribute__((ext_vector_type(4))) float f32x4;

#define MFMA16(a, b, c) __builtin_amdgcn_mfma_f32_16x16x32_bf16((a), (b), (c), 0, 0, 0)

__device__ __forceinline__ float gelu_f(float x) {
    return 0.5f * x * (1.0f + erff(x * 0.7071067811865475f));
}

__device__ __forceinline__ ushort f2bf_rn(float f) {
    uint u = __float_as_uint(f);
    return (ushort)((u + 0x7FFFu + ((u >> 16) & 1u)) >> 16);
}
__device__ __forceinline__ float bf2f(ushort h) {
    return __uint_as_float(((uint)h) << 16);
}

// split f32x8 -> bf16 hi + bf16 lo fragments (bf16x3 trick: f ~= hi + lo, |resid| ~ 2^-17|f|)
__device__ __forceinline__ void cvt_hilo(float4 x0, float4 x1, bf16x8& h, bf16x8& l) {
    float f[8] = {x0.x, x0.y, x0.z, x0.w, x1.x, x1.y, x1.z, x1.w};
    #pragma unroll
    for (int j = 0; j < 8; ++j) {
        ushort hb = f2bf_rn(f[j]);
        h[j] = (short)hb;
        l[j] = (short)f2bf_rn(f[j] - bf2f(hb));
    }
}

// ---------------- fold + pack kernels ----------------
// Fold BN scale into W and pack into MFMA B-fragment order, split bf16 hi/lo.
// Fragment layout for 16x16x32: lane ln holds col = c*16+(ln&15), k = st*32+(ln>>4)*8+j.
// Element (k,col) of folded W -> plane offset ((c*(K/32)+st)*64+ln)*8+j.
__global__ void pack_w(const float* __restrict__ W, const float* __restrict__ g,
                       const float* __restrict__ v, ushort* __restrict__ hi,
                       ushort* __restrict__ lo, int K) {
    int idx = blockIdx.x * 256 + threadIdx.x;
    if (idx >= K * DD) return;
    int k = idx >> 7, col = idx & 127;
    float s = g[k] * rsqrtf(v[k] + BN_EPS);
    float f = s * W[idx];
    int S = K >> 5;
    int st = k >> 5, gq = (k >> 3) & 3, j = k & 7;
    int c = col >> 4, ln = (gq << 4) | (col & 15);
    int o = ((c * S + st) * 64 + ln) * 8 + j;
    ushort hb = f2bf_rn(f);
    hi[o] = hb;
    lo[o] = f2bf_rn(f - bf2f(hb));
}

// b'[j] = bias[j] + sum_k (b[k]-m[k]*s[k]) * W[k][j]   (kept f32, added post-MFMA)
__global__ void fold_b(const float* __restrict__ W, const float* __restrict__ g,
                       const float* __restrict__ bb, const float* __restrict__ m,
                       const float* __restrict__ v, const float* __restrict__ bias,
                       float* __restrict__ bf, int K) {
    int j = threadIdx.x;  // 128 threads
    float acc = 0.f;
    for (int k = 0; k < K; ++k) {
        float s = g[k] * rsqrtf(v[k] + BN_EPS);
        float t = bb[k] - m[k] * s;
        acc = fmaf(t, W[k * DD + j], acc);
    }
    bf[j] = bias[j] + acc;
}

// ---------------- edge kernel: gather -> MFMA FFN(2 layers) -> *ew -> atomic scatter ----
// 128 edges/block, 8 waves x 16 rows. A from global gather, B from packed planes (L2-hot),
// layer1->2 handoff via LDS Y[128][132] f32.
__global__ __launch_bounds__(512, 4) void edge_kernel(
    const float* __restrict__ reps, const int* __restrict__ edges,
    const float* __restrict__ ew,
    const ushort* __restrict__ W1h, const ushort* __restrict__ W1l, const float* __restrict__ B1,
    const ushort* __restrict__ W2h, const ushort* __restrict__ W2l, const float* __restrict__ B2,
    float* __restrict__ agg)
{
    __shared__ float Y[128 * 132];
    const int t = threadIdx.x;
    const int w = t >> 6, l = t & 63, lg = l >> 4, lr = l & 15;
    const int e0 = blockIdx.x * 128;
    const int erow = e0 + w * 16;

    float b1v[8], b2v[8];
    #pragma unroll
    for (int c = 0; c < 8; ++c) { b1v[c] = B1[c * 16 + lr]; b2v[c] = B2[c * 16 + lr]; }

    const int nb = edges[EE + erow + lr];  // neighbour (edges row 1)
    const float* src = reps + (size_t)nb * DD;

    f32x4 acc[8];
    #pragma unroll
    for (int c = 0; c < 8; ++c) acc[c] = (f32x4)(0.f);

    // ---- layer 1 ----
    #pragma unroll
    for (int s = 0; s < 4; ++s) {
        float4 x0 = *reinterpret_cast<const float4*>(src + s * 32 + lg * 8);
        float4 x1 = *reinterpret_cast<const float4*>(src + s * 32 + lg * 8 + 4);
        bf16x8 ah, al;
        cvt_hilo(x0, x1, ah, al);
        #pragma unroll
        for (int c = 0; c < 8; ++c) {
            bf16x8 bh = *reinterpret_cast<const bf16x8*>(W1h + (size_t)((c * 4 + s) * 64 + l) * 8);
            bf16x8 bl = *reinterpret_cast<const bf16x8*>(W1l + (size_t)((c * 4 + s) * 64 + l) * 8);
            acc[c] = MFMA16(al, bh, acc[c]);
            acc[c] = MFMA16(ah, bl, acc[c]);
            acc[c] = MFMA16(ah, bh, acc[c]);
        }
    }
    // bias + GELU -> Y (D layout: row=(l>>4)*4+i, col=c*16+(l&15))
    #pragma unroll
    for (int c = 0; c < 8; ++c) {
        #pragma unroll
        for (int i = 0; i < 4; ++i) {
            float yv = gelu_f(acc[c][i] + b1v[c]);
            Y[(w * 16 + lg * 4 + i) * 132 + c * 16 + lr] = yv;
        }
    }
    __syncthreads();

    // ---- layer 2 ----
    #pragma unroll
    for (int c = 0; c < 8; ++c) acc[c] = (f32x4)(0.f);
    const float* yr = Y + (w * 16 + lr) * 132;
    #pragma unroll
    for (int s = 0; s < 4; ++s) {
        float4 y0 = *reinterpret_cast<const float4*>(yr + s * 32 + lg * 8);
        float4 y1 = *reinterpret_cast<const float4*>(yr + s * 32 + lg * 8 + 4);
        bf16x8 ah, al;
        cvt_hilo(y0, y1, ah, al);
        #pragma unroll
        for (int c = 0; c < 8; ++c) {
            bf16x8 bh = *reinterpret_cast<const bf16x8*>(W2h + (size_t)((c * 4 + s) * 64 + l) * 8);
            bf16x8 bl = *reinterpret_cast<const bf16x8*>(W2l + (size_t)((c * 4 + s) * 64 + l) * 8);
            acc[c] = MFMA16(al, bh, acc[c]);
            acc[c] = MFMA16(ah, bl, acc[c]);
            acc[c] = MFMA16(ah, bh, acc[c]);
        }
    }

    // ---- bias + GELU + *ew + atomic scatter ----
    float ewv[4];
    int nd[4];
    #pragma unroll
    for (int i = 0; i < 4; ++i) {
        int e = erow + lg * 4 + i;
        ewv[i] = ew[e];
        nd[i] = edges[e];  // dest node (edges row 0)
    }
    #pragma unroll
    for (int c = 0; c < 8; ++c) {
        #pragma unroll
        for (int i = 0; i < 4; ++i) {
            float vv = gelu_f(acc[c][i] + b2v[c]) * ewv[i];
            atomicAdd(agg + (size_t)nd[i] * DD + c * 16 + lr, vv);
        }
    }
}

// ---------------- node kernel: concat -> MFMA FFN(2 layers) -> L2 normalize ----
// 128 nodes/block, 8 waves x 16 rows. Layer1 K=256 (reps | agg), layer2 K=128.
__global__ __launch_bounds__(512, 4) void node_kernel(
    const float* __restrict__ reps, const float* __restrict__ agg,
    const ushort* __restrict__ U1h, const ushort* __restrict__ U1l, const float* __restrict__ C1,
    const ushort* __restrict__ U2h, const ushort* __restrict__ U2l, const float* __restrict__ C2,
    float* __restrict__ out)
{
    __shared__ float Y[128 * 132];
    const int t = threadIdx.x;
    const int w = t >> 6, l = t & 63, lg = l >> 4, lr = l & 15;
    const int n0 = blockIdx.x * 128;
    int n = n0 + w * 16 + lr;
    int nc = n < NN ? n : NN - 1;  // clamp tail loads; stores guarded

    float c1v[8], c2v[8];
    #pragma unroll
    for (int c = 0; c < 8; ++c) { c1v[c] = C1[c * 16 + lr]; c2v[c] = C2[c * 16 + lr]; }

    f32x4 acc[8];
    #pragma unroll
    for (int c = 0; c < 8; ++c) acc[c] = (f32x4)(0.f);

    // ---- update layer 1: K=256, concat [reps | agg] ----
    #pragma unroll
    for (int s = 0; s < 8; ++s) {
        int kb = s * 32 + lg * 8;
        const float* sp = (kb < 128) ? (reps + (size_t)nc * DD + kb)
                                     : (agg + (size_t)nc * DD + (kb - 128));
        float4 x0 = *reinterpret_cast<const float4*>(sp);
        float4 x1 = *reinterpret_cast<const float4*>(sp + 4);
        bf16x8 ah, al;
        cvt_hilo(x0, x1, ah, al);
        #pragma unroll
        for (int c = 0; c < 8; ++c) {
            bf16x8 bh = *reinterpret_cast<const bf16x8*>(U1h + (size_t)((c * 8 + s) * 64 + l) * 8);
            bf16x8 bl = *reinterpret_cast<const bf16x8*>(U1l + (size_t)((c * 8 + s) * 64 + l) * 8);
            acc[c] = MFMA16(al, bh, acc[c]);
            acc[c] = MFMA16(ah, bl, acc[c]);
            acc[c] = MFMA16(ah, bh, acc[c]);
        }
    }
    #pragma unroll
    for (int c = 0; c < 8; ++c) {
        #pragma unroll
        for (int i = 0; i < 4; ++i) {
            float yv = gelu_f(acc[c][i] + c1v[c]);
            Y[(w * 16 + lg * 4 + i) * 132 + c * 16 + lr] = yv;
        }
    }
    __syncthreads();

    // ---- update layer 2: K=128 ----
    #pragma unroll
    for (int c = 0; c < 8; ++c) acc[c] = (f32x4)(0.f);
    const float* yr = Y + (w * 16 + lr) * 132;
    #pragma unroll
    for (int s = 0; s < 4; ++s) {
        float4 y0 = *reinterpret_cast<const float4*>(yr + s * 32 + lg * 8);
        float4 y1 = *reinterpret_cast<const float4*>(yr + s * 32 + lg * 8 + 4);
        bf16x8 ah, al;
        cvt_hilo(y0, y1, ah, al);
        #pragma unroll
        for (int c = 0; c < 8; ++c) {
            bf16x8 bh = *reinterpret_cast<const bf16x8*>(U2h + (size_t)((c * 4 + s) * 64 + l) * 8);
            bf16x8 bl = *reinterpret_cast<const bf16x8*>(U2l + (size_t)((c * 4 + s) * 64 + l) * 8);
            acc[c] = MFMA16(al, bh, acc[c]);
            acc[c] = MFMA16(ah, bl, acc[c]);
            acc[c] = MFMA16(ah, bh, acc[c]);
        }
    }

    // ---- bias + GELU + L2 normalize + store ----
    float ssq[4] = {0.f, 0.f, 0.f, 0.f};
    #pragma unroll
    for (int c = 0; c < 8; ++c) {
        #pragma unroll
        for (int i = 0; i < 4; ++i) {
            float vv = gelu_f(acc[c][i] + c2v[c]);
            acc[c][i] = vv;
            ssq[i] = fmaf(vv, vv, ssq[i]);
        }
    }
    // row r = w*16 + lg*4 + i lives in the 16 lanes of group lg, reg i
    #pragma unroll
    for (int i = 0; i < 4; ++i) {
        #pragma unroll
        for (int msk = 1; msk < 16; msk <<= 1) ssq[i] += __shfl_xor(ssq[i], msk);
        ssq[i] = rsqrtf(fmaxf(ssq[i], 1e-12f));
    }
    const int nrow = n0 + w * 16 + lg * 4;
    #pragma unroll
    for (int i = 0; i < 4; ++i) {
        if (nrow + i < NN) {
            #pragma unroll
            for (int c = 0; c < 8; ++c)
                out[(size_t)(nrow + i) * DD + c * 16 + lr] = acc[c][i] * ssq[i];
        }
    }
}

// ---------------- launch ----------------
extern "C" void kernel_launch(void* const* d_in, const int* in_sizes, int n_in,
                              void* d_out, int out_size, void* d_ws, size_t ws_size,
                              hipStream_t stream)
{
    const float* reps = (const float*)d_in[0];
    const int*   edges = (const int*)d_in[1];
    const float* ew   = (const float*)d_in[2];
    const float* bn1g = (const float*)d_in[3];
    const float* bn1b = (const float*)d_in[4];
    const float* bn1m = (const float*)d_in[5];
    const float* bn1v = (const float*)d_in[6];
    const float* w1   = (const float*)d_in[7];
    const float* b1   = (const float*)d_in[8];
    const float* bn2g = (const float*)d_in[9];
    const float* bn2b = (const float*)d_in[10];
    const float* bn2m = (const float*)d_in[11];
    const float* bn2v = (const float*)d_in[12];
    const float* w2   = (const float*)d_in[13];
    const float* b2   = (const float*)d_in[14];
    const float* ubn1g = (const float*)d_in[15];
    const float* ubn1b = (const float*)d_in[16];
    const float* ubn1m = (const float*)d_in[17];
    const float* ubn1v = (const float*)d_in[18];
    const float* u1    = (const float*)d_in[19];
    const float* ub1   = (const float*)d_in[20];
    const float* ubn2g = (const float*)d_in[21];
    const float* ubn2b = (const float*)d_in[22];
    const float* ubn2m = (const float*)d_in[23];
    const float* ubn2v = (const float*)d_in[24];
    const float* u2    = (const float*)d_in[25];
    const float* ub2   = (const float*)d_in[26];

    // workspace layout
    float* ws  = (float*)d_ws;
    float* agg = ws;                       // 6,400,000 f32
    float* B1f = ws + 6400000;             // 128
    float* B2f = B1f + 128;
    float* C1f = B2f + 128;
    float* C2f = C1f + 128;
    ushort* up  = (ushort*)(C2f + 128);    // byte offset 25,602,048 (16B aligned)
    ushort* W1h = up;                      // 16384 each
    ushort* W1l = W1h + 16384;
    ushort* W2h = W1l + 16384;
    ushort* W2l = W2h + 16384;
    ushort* U1h = W2l + 16384;             // 32768 each
    ushort* U1l = U1h + 32768;
    ushort* U2h = U1l + 32768;             // 16384 each
    ushort* U2l = U2h + 16384;
    if (ws_size < (size_t)6400512 * 4 + (size_t)163840 * 2) return;

    pack_w<<<64,  256, 0, stream>>>(w1, bn1g, bn1v, W1h, W1l, 128);
    fold_b<<<1,   128, 0, stream>>>(w1, bn1g, bn1b, bn1m, bn1v, b1, B1f, 128);
    pack_w<<<64,  256, 0, stream>>>(w2, bn2g, bn2v, W2h, W2l, 128);
    fold_b<<<1,   128, 0, stream>>>(w2, bn2g, bn2b, bn2m, bn2v, b2, B2f, 128);
    pack_w<<<128, 256, 0, stream>>>(u1, ubn1g, ubn1v, U1h, U1l, 256);
    fold_b<<<1,   128, 0, stream>>>(u1, ubn1g, ubn1b, ubn1m, ubn1v, ub1, C1f, 256);
    pack_w<<<64,  256, 0, stream>>>(u2, ubn2g, ubn2v, U2h, U2l, 128);
    fold_b<<<1,   128, 0, stream>>>(u2, ubn2g, ubn2b, ubn2m, ubn2v, ub2, C2f, 128);

    hipMemsetAsync(agg, 0, (size_t)NN * DD * sizeof(float), stream);

    edge_kernel<<<EE / 128, 512, 0, stream>>>(reps, edges, ew, W1h, W1l, B1f,
                                              W2h, W2l, B2f, agg);
    node_kernel<<<(NN + 127) / 128, 512, 0, stream>>>(reps, agg, U1h, U1l, C1f,
                                                      U2h, U2l, C2f, (float*)d_out);
}

// Round 6
// 617.058 us; speedup vs baseline: 2.7507x; 1.0640x over previous
//
#include <hip/hip_runtime.h>
#include <hip/hip_bf16.h>
#include <math.h>

#define NN 50000
#define DD 128
#define EE 800000

static constexpr float BN_EPS = 1e-3f;

typedef __attribute__((ext_vector_type(8))) short bf16x8;
typedef __attribute__((ext_vector_type(4))) float f32x4;

#define MFMA16(a, b, c) __builtin_amdgcn_mfma_f32_16x16x32_bf16((a), (b), (c), 0, 0, 0)

// fast exact-grade GELU: Abramowitz-Stegun 7.1.26 erf (abs err 1.5e-7)
__device__ __forceinline__ float gelu_f(float x) {
    float ax = fabsf(x) * 0.7071067811865475f;
    float t = __builtin_amdgcn_rcpf(fmaf(0.3275911f, ax, 1.0f));
    float p = t * fmaf(t, fmaf(t, fmaf(t, fmaf(t, 1.061405429f, -1.453152027f),
                                       1.421413741f), -0.284496736f), 0.254829592f);
    float e = __expf(-ax * ax);
    float er = fmaf(-p, e, 1.0f);        // erf(|x|/sqrt2) for ax>=0
    float s = copysignf(er, x);
    return 0.5f * x * (1.0f + s);
}

__device__ __forceinline__ ushort f2bf_rn(float f) {
    uint u = __float_as_uint(f);
    return (ushort)((u + 0x7FFFu + ((u >> 16) & 1u)) >> 16);
}
__device__ __forceinline__ float bf2f(ushort h) {
    return __uint_as_float(((uint)h) << 16);
}

// packed pair f32->bf16 RNE (compiler emits v_cvt_pk_bf16_f32)
__device__ __forceinline__ uint pk2(float a, float b) {
    __hip_bfloat162 t = __float22bfloat162_rn(make_float2(a, b));
    uint r;
    __builtin_memcpy(&r, &t, 4);
    return r;
}

// split f32x8 -> bf16 hi + bf16 lo fragments (f ~= hi + lo, |resid| ~ 2^-17|f|)
__device__ __forceinline__ void cvt_hilo(float4 x0, float4 x1, bf16x8& h, bf16x8& l) {
    float f[8] = {x0.x, x0.y, x0.z, x0.w, x1.x, x1.y, x1.z, x1.w};
    union U { uint u[4]; bf16x8 v; } uh, ul;
    #pragma unroll
    for (int j = 0; j < 4; ++j) {
        uint p = pk2(f[2 * j], f[2 * j + 1]);
        uh.u[j] = p;
        float h0 = __uint_as_float(p << 16);
        float h1 = __uint_as_float(p & 0xFFFF0000u);
        ul.u[j] = pk2(f[2 * j] - h0, f[2 * j + 1] - h1);
    }
    h = uh.v;
    l = ul.v;
}

// ---------------- fold + pack kernels ----------------
// Fold BN scale into W and pack into MFMA B-fragment order, split bf16 hi/lo.
// Fragment layout for 16x16x32: lane ln holds col = c*16+(ln&15), k = st*32+(ln>>4)*8+j.
// Element (k,col) of folded W -> plane offset ((c*(K/32)+st)*64+ln)*8+j.
__global__ void pack_w(const float* __restrict__ W, const float* __restrict__ g,
                       const float* __restrict__ v, ushort* __restrict__ hi,
                       ushort* __restrict__ lo, int K) {
    int idx = blockIdx.x * 256 + threadIdx.x;
    if (idx >= K * DD) return;
    int k = idx >> 7, col = idx & 127;
    float s = g[k] * rsqrtf(v[k] + BN_EPS);
    float f = s * W[idx];
    int S = K >> 5;
    int st = k >> 5, gq = (k >> 3) & 3, j = k & 7;
    int c = col >> 4, ln = (gq << 4) | (col & 15);
    int o = ((c * S + st) * 64 + ln) * 8 + j;
    ushort hb = f2bf_rn(f);
    hi[o] = hb;
    lo[o] = f2bf_rn(f - bf2f(hb));
}

// b'[j] = bias[j] + sum_k (b[k]-m[k]*s[k]) * W[k][j]   (kept f32, added post-MFMA)
__global__ void fold_b(const float* __restrict__ W, const float* __restrict__ g,
                       const float* __restrict__ bb, const float* __restrict__ m,
                       const float* __restrict__ v, const float* __restrict__ bias,
                       float* __restrict__ bf, int K) {
    int j = threadIdx.x;  // 128 threads
    float acc = 0.f;
    for (int k = 0; k < K; ++k) {
        float s = g[k] * rsqrtf(v[k] + BN_EPS);
        float t = bb[k] - m[k] * s;
        acc = fmaf(t, W[k * DD + j], acc);
    }
    bf[j] = bias[j] + acc;
}

// ---------------- edge kernel: gather -> MFMA FFN(2 layers) -> *ew -> atomic scatter ----
// 128 edges/block, 8 waves x 16 rows. Each wave owns rows w*16..w*16+15 of Y — no
// cross-wave LDS sharing, so NO __syncthreads (intra-wave lgkmcnt ordering suffices).
__global__ __launch_bounds__(512, 4) void edge_kernel(
    const float* __restrict__ reps, const int* __restrict__ edges,
    const float* __restrict__ ew,
    const ushort* __restrict__ W1h, const ushort* __restrict__ W1l, const float* __restrict__ B1,
    const ushort* __restrict__ W2h, const ushort* __restrict__ W2l, const float* __restrict__ B2,
    float* __restrict__ agg)
{
    __shared__ float Y[128 * 132];
    const int t = threadIdx.x;
    const int w = t >> 6, l = t & 63, lg = l >> 4, lr = l & 15;
    const int e0 = blockIdx.x * 128;
    const int erow = e0 + w * 16;

    float b1v[8], b2v[8];
    #pragma unroll
    for (int c = 0; c < 8; ++c) { b1v[c] = B1[c * 16 + lr]; b2v[c] = B2[c * 16 + lr]; }

    const int nb = edges[EE + erow + lr];  // neighbour (edges row 1)
    const float* src = reps + (size_t)nb * DD;

    // prefetch edge weight + dest node for the scatter (hide latency under MFMA)
    float ewv[4];
    int nd[4];
    #pragma unroll
    for (int i = 0; i < 4; ++i) {
        int e = erow + lg * 4 + i;
        ewv[i] = ew[e];
        nd[i] = edges[e];  // dest node (edges row 0)
    }

    f32x4 acc[8];
    #pragma unroll
    for (int c = 0; c < 8; ++c) acc[c] = (f32x4)(0.f);

    // ---- layer 1 ----
    #pragma unroll
    for (int s = 0; s < 4; ++s) {
        float4 x0 = *reinterpret_cast<const float4*>(src + s * 32 + lg * 8);
        float4 x1 = *reinterpret_cast<const float4*>(src + s * 32 + lg * 8 + 4);
        bf16x8 ah, al;
        cvt_hilo(x0, x1, ah, al);
        #pragma unroll
        for (int c = 0; c < 8; ++c) {
            bf16x8 bh = *reinterpret_cast<const bf16x8*>(W1h + (size_t)((c * 4 + s) * 64 + l) * 8);
            bf16x8 bl = *reinterpret_cast<const bf16x8*>(W1l + (size_t)((c * 4 + s) * 64 + l) * 8);
            acc[c] = MFMA16(al, bh, acc[c]);
            acc[c] = MFMA16(ah, bl, acc[c]);
            acc[c] = MFMA16(ah, bh, acc[c]);
        }
    }
    // bias + GELU -> Y (D layout: row=(l>>4)*4+i, col=c*16+(l&15)); own-wave rows only
    #pragma unroll
    for (int c = 0; c < 8; ++c) {
        #pragma unroll
        for (int i = 0; i < 4; ++i) {
            float yv = gelu_f(acc[c][i] + b1v[c]);
            Y[(w * 16 + lg * 4 + i) * 132 + c * 16 + lr] = yv;
        }
    }

    // ---- layer 2 ---- (same-wave LDS dependency; compiler inserts lgkmcnt wait)
    #pragma unroll
    for (int c = 0; c < 8; ++c) acc[c] = (f32x4)(0.f);
    const float* yr = Y + (w * 16 + lr) * 132;
    #pragma unroll
    for (int s = 0; s < 4; ++s) {
        float4 y0 = *reinterpret_cast<const float4*>(yr + s * 32 + lg * 8);
        float4 y1 = *reinterpret_cast<const float4*>(yr + s * 32 + lg * 8 + 4);
        bf16x8 ah, al;
        cvt_hilo(y0, y1, ah, al);
        #pragma unroll
        for (int c = 0; c < 8; ++c) {
            bf16x8 bh = *reinterpret_cast<const bf16x8*>(W2h + (size_t)((c * 4 + s) * 64 + l) * 8);
            bf16x8 bl = *reinterpret_cast<const bf16x8*>(W2l + (size_t)((c * 4 + s) * 64 + l) * 8);
            acc[c] = MFMA16(al, bh, acc[c]);
            acc[c] = MFMA16(ah, bl, acc[c]);
            acc[c] = MFMA16(ah, bh, acc[c]);
        }
    }

    // ---- bias + GELU + *ew + atomic scatter ----
    #pragma unroll
    for (int i = 0; i < 4; ++i) {
        float* dst = agg + (size_t)nd[i] * DD + lr;
        #pragma unroll
        for (int c = 0; c < 8; ++c) {
            float vv = gelu_f(acc[c][i] + b2v[c]) * ewv[i];
            atomicAdd(dst + c * 16, vv);
        }
    }
}

// ---------------- node kernel: concat -> MFMA FFN(2 layers) -> L2 normalize ----
// 64 nodes/block, 4 waves x 16 rows (782 blocks -> ~3 blocks/CU). No __syncthreads
// (per-wave Y slices). Layer1 K=256 (reps | agg), layer2 K=128.
__global__ __launch_bounds__(256, 4) void node_kernel(
    const float* __restrict__ reps, const float* __restrict__ agg,
    const ushort* __restrict__ U1h, const ushort* __restrict__ U1l, const float* __restrict__ C1,
    const ushort* __restrict__ U2h, const ushort* __restrict__ U2l, const float* __restrict__ C2,
    float* __restrict__ out)
{
    __shared__ float Y[64 * 132];
    const int t = threadIdx.x;
    const int w = t >> 6, l = t & 63, lg = l >> 4, lr = l & 15;
    const int n0 = blockIdx.x * 64;
    int n = n0 + w * 16 + lr;
    int nc = n < NN ? n : NN - 1;  // clamp tail loads; stores guarded

    float c1v[8], c2v[8];
    #pragma unroll
    for (int c = 0; c < 8; ++c) { c1v[c] = C1[c * 16 + lr]; c2v[c] = C2[c * 16 + lr]; }

    f32x4 acc[8];
    #pragma unroll
    for (int c = 0; c < 8; ++c) acc[c] = (f32x4)(0.f);

    // ---- update layer 1: K=256, concat [reps | agg] ----
    #pragma unroll
    for (int s = 0; s < 8; ++s) {
        int kb = s * 32 + lg * 8;
        const float* sp = (kb < 128) ? (reps + (size_t)nc * DD + kb)
                                     : (agg + (size_t)nc * DD + (kb - 128));
        float4 x0 = *reinterpret_cast<const float4*>(sp);
        float4 x1 = *reinterpret_cast<const float4*>(sp + 4);
        bf16x8 ah, al;
        cvt_hilo(x0, x1, ah, al);
        #pragma unroll
        for (int c = 0; c < 8; ++c) {
            bf16x8 bh = *reinterpret_cast<const bf16x8*>(U1h + (size_t)((c * 8 + s) * 64 + l) * 8);
            bf16x8 bl = *reinterpret_cast<const bf16x8*>(U1l + (size_t)((c * 8 + s) * 64 + l) * 8);
            acc[c] = MFMA16(al, bh, acc[c]);
            acc[c] = MFMA16(ah, bl, acc[c]);
            acc[c] = MFMA16(ah, bh, acc[c]);
        }
    }
    #pragma unroll
    for (int c = 0; c < 8; ++c) {
        #pragma unroll
        for (int i = 0; i < 4; ++i) {
            float yv = gelu_f(acc[c][i] + c1v[c]);
            Y[(w * 16 + lg * 4 + i) * 132 + c * 16 + lr] = yv;
        }
    }

    // ---- update layer 2: K=128 ----
    #pragma unroll
    for (int c = 0; c < 8; ++c) acc[c] = (f32x4)(0.f);
    const float* yr = Y + (w * 16 + lr) * 132;
    #pragma unroll
    for (int s = 0; s < 4; ++s) {
        float4 y0 = *reinterpret_cast<const float4*>(yr + s * 32 + lg * 8);
        float4 y1 = *reinterpret_cast<const float4*>(yr + s * 32 + lg * 8 + 4);
        bf16x8 ah, al;
        cvt_hilo(y0, y1, ah, al);
        #pragma unroll
        for (int c = 0; c < 8; ++c) {
            bf16x8 bh = *reinterpret_cast<const bf16x8*>(U2h + (size_t)((c * 4 + s) * 64 + l) * 8);
            bf16x8 bl = *reinterpret_cast<const bf16x8*>(U2l + (size_t)((c * 4 + s) * 64 + l) * 8);
            acc[c] = MFMA16(al, bh, acc[c]);
            acc[c] = MFMA16(ah, bl, acc[c]);
            acc[c] = MFMA16(ah, bh, acc[c]);
        }
    }

    // ---- bias + GELU + L2 normalize + store ----
    float ssq[4] = {0.f, 0.f, 0.f, 0.f};
    #pragma unroll
    for (int c = 0; c < 8; ++c) {
        #pragma unroll
        for (int i = 0; i < 4; ++i) {
            float vv = gelu_f(acc[c][i] + c2v[c]);
            acc[c][i] = vv;
            ssq[i] = fmaf(vv, vv, ssq[i]);
        }
    }
    // row r = w*16 + lg*4 + i lives in the 16 lanes of group lg, reg i
    #pragma unroll
    for (int i = 0; i < 4; ++i) {
        #pragma unroll
        for (int msk = 1; msk < 16; msk <<= 1) ssq[i] += __shfl_xor(ssq[i], msk);
        ssq[i] = rsqrtf(fmaxf(ssq[i], 1e-12f));
    }
    const int nrow = n0 + w * 16 + lg * 4;
    #pragma unroll
    for (int i = 0; i < 4; ++i) {
        if (nrow + i < NN) {
            #pragma unroll
            for (int c = 0; c < 8; ++c)
                out[(size_t)(nrow + i) * DD + c * 16 + lr] = acc[c][i] * ssq[i];
        }
    }
}

// ---------------- launch ----------------
extern "C" void kernel_launch(void* const* d_in, const int* in_sizes, int n_in,
                              void* d_out, int out_size, void* d_ws, size_t ws_size,
                              hipStream_t stream)
{
    const float* reps = (const float*)d_in[0];
    const int*   edges = (const int*)d_in[1];
    const float* ew   = (const float*)d_in[2];
    const float* bn1g = (const float*)d_in[3];
    const float* bn1b = (const float*)d_in[4];
    const float* bn1m = (const float*)d_in[5];
    const float* bn1v = (const float*)d_in[6];
    const float* w1   = (const float*)d_in[7];
    const float* b1   = (const float*)d_in[8];
    const float* bn2g = (const float*)d_in[9];
    const float* bn2b = (const float*)d_in[10];
    const float* bn2m = (const float*)d_in[11];
    const float* bn2v = (const float*)d_in[12];
    const float* w2   = (const float*)d_in[13];
    const float* b2   = (const float*)d_in[14];
    const float* ubn1g = (const float*)d_in[15];
    const float* ubn1b = (const float*)d_in[16];
    const float* ubn1m = (const float*)d_in[17];
    const float* ubn1v = (const float*)d_in[18];
    const float* u1    = (const float*)d_in[19];
    const float* ub1   = (const float*)d_in[20];
    const float* ubn2g = (const float*)d_in[21];
    const float* ubn2b = (const float*)d_in[22];
    const float* ubn2m = (const float*)d_in[23];
    const float* ubn2v = (const float*)d_in[24];
    const float* u2    = (const float*)d_in[25];
    const float* ub2   = (const float*)d_in[26];

    // workspace layout
    float* ws  = (float*)d_ws;
    float* agg = ws;                       // 6,400,000 f32
    float* B1f = ws + 6400000;             // 128
    float* B2f = B1f + 128;
    float* C1f = B2f + 128;
    float* C2f = C1f + 128;
    ushort* up  = (ushort*)(C2f + 128);    // byte offset 25,602,048 (16B aligned)
    ushort* W1h = up;                      // 16384 each
    ushort* W1l = W1h + 16384;
    ushort* W2h = W1l + 16384;
    ushort* W2l = W2h + 16384;
    ushort* U1h = W2l + 16384;             // 32768 each
    ushort* U1l = U1h + 32768;
    ushort* U2h = U1l + 32768;             // 16384 each
    ushort* U2l = U2h + 16384;
    if (ws_size < (size_t)6400512 * 4 + (size_t)163840 * 2) return;

    pack_w<<<64,  256, 0, stream>>>(w1, bn1g, bn1v, W1h, W1l, 128);
    fold_b<<<1,   128, 0, stream>>>(w1, bn1g, bn1b, bn1m, bn1v, b1, B1f, 128);
    pack_w<<<64,  256, 0, stream>>>(w2, bn2g, bn2v, W2h, W2l, 128);
    fold_b<<<1,   128, 0, stream>>>(w2, bn2g, bn2b, bn2m, bn2v, b2, B2f, 128);
    pack_w<<<128, 256, 0, stream>>>(u1, ubn1g, ubn1v, U1h, U1l, 256);
    fold_b<<<1,   128, 0, stream>>>(u1, ubn1g, ubn1b, ubn1m, ubn1v, ub1, C1f, 256);
    pack_w<<<64,  256, 0, stream>>>(u2, ubn2g, ubn2v, U2h, U2l, 128);
    fold_b<<<1,   128, 0, stream>>>(u2, ubn2g, ubn2b, ubn2m, ubn2v, ub2, C2f, 128);

    (void)hipMemsetAsync(agg, 0, (size_t)NN * DD * sizeof(float), stream);

    edge_kernel<<<EE / 128, 512, 0, stream>>>(reps, edges, ew, W1h, W1l, B1f,
                                              W2h, W2l, B2f, agg);
    node_kernel<<<(NN + 63) / 64, 256, 0, stream>>>(reps, agg, U1h, U1l, C1f,
                                                    U2h, U2l, C2f, (float*)d_out);
}